// Round 16
// baseline (319.179 us; speedup 1.0000x reference)
//
#include <hip/hip_runtime.h>
#include <math.h>

#define NT 4096
#define NS 2048
#define DDIM 512
#define KN 5
#define NTILES 528   // 32*33/2 triangle tiles of 128x128
#define NBLK 529     // mega-kernel grid (block 0 = scan block)

typedef __bf16 bf16x8 __attribute__((ext_vector_type(8)));
typedef float f32x4 __attribute__((ext_vector_type(4)));
typedef unsigned short u16x8 __attribute__((ext_vector_type(8)));

static __device__ inline unsigned short f2bf(float x) {
    unsigned u = __float_as_uint(x);
    unsigned r = (u + 0x7fffu + ((u >> 16) & 1u)) >> 16;
    return (unsigned short)r;
}
static __device__ inline float bf2f(unsigned short h) {
    return __uint_as_float(((unsigned)h) << 16);
}

static __device__ inline void tri_map(int b, int& bx, int& by) {
    int x = (int)((sqrtf(8.0f * (float)b + 1.0f) - 1.0f) * 0.5f);
    while ((x + 1) * (x + 2) / 2 <= b) ++x;
    while (x * (x + 1) / 2 > b) --x;
    bx = x;
    by = b - x * (x + 1) / 2;
}
static __device__ inline int xcd_tile(int bb) {
    return (bb & 7) * 66 + (bb >> 3);            // 528 = 8*66, bijective
}

static __device__ inline unsigned aload(unsigned* p) { return atomicAdd(p, 0u); }

// wscan over a (block-local) histogram: find bin holding rank r.
static __device__ inline void wscan(const unsigned* __restrict__ h, int C, unsigned r,
                                    unsigned& bin, unsigned& rem)
{
    int lane = threadIdx.x;      // caller guarantees tid < 64
    unsigned s = 0;
    for (int i = 0; i < C; ++i) s += h[lane * C + i];
    unsigned x = s;
    #pragma unroll
    for (int off = 1; off < 64; off <<= 1) {
        unsigned y = __shfl_up(x, off);
        if (lane >= off) x += y;
    }
    unsigned base = x - s;
    bool has = (r >= base) && (r < base + s);
    unsigned long long mm = __ballot(has);
    int leader = __ffsll(mm) - 1;
    unsigned b = 0, cb = 0;
    if (lane == leader) {
        unsigned cc = base;
        for (int i = 0; i < C; ++i) {
            unsigned hv = h[lane * C + i];
            if (r < cc + hv) { b = lane * C + i; cb = cc; break; }
            cc += hv;
        }
    }
    bin = __shfl(b, leader);
    rem = r - __shfl(cb, leader);
}

// ---------------------------------------------------------------- beta solve
static __device__ void beta_solve(const float* __restrict__ g,
                                  const float* __restrict__ beta_in,
                                  float* __restrict__ beta_out)
{
    int lane = threadIdx.x;
    float gs[KN] = {0, 0, 0, 0, 0};
    float gg[15];
    #pragma unroll
    for (int i = 0; i < 15; ++i) gg[i] = 0.0f;
    for (int p = lane; p < 1024; p += 64) {
        float gv[KN];
        #pragma unroll
        for (int k = 0; k < KN; ++k) gv[k] = g[(size_t)p * KN + k];
        int idx = 0;
        #pragma unroll
        for (int a2 = 0; a2 < KN; ++a2) {
            gs[a2] += gv[a2];
            #pragma unroll
            for (int b2 = a2; b2 < KN; ++b2) gg[idx++] += gv[a2] * gv[b2];
        }
    }
    #pragma unroll
    for (int m = 32; m > 0; m >>= 1) {
        #pragma unroll
        for (int k = 0; k < KN; ++k) gs[k] += __shfl_xor(gs[k], m);
        #pragma unroll
        for (int i = 0; i < 15; ++i) gg[i] += __shfl_xor(gg[i], m);
    }
    if (lane != 0) return;

    float Q[KN][KN], gm[KN];
    #pragma unroll
    for (int k = 0; k < KN; ++k) gm[k] = gs[k] * (1.0f / 1024.0f);
    int idx = 0;
    #pragma unroll
    for (int a2 = 0; a2 < KN; ++a2)
        #pragma unroll
        for (int b2 = a2; b2 < KN; ++b2) {
            float qv = gg[idx++] * (1.0f / 1024.0f) - gm[a2] * gm[b2];
            Q[a2][b2] = qv; Q[b2][a2] = qv;
        }
    #pragma unroll
    for (int k = 0; k < KN; ++k) Q[k][k] += 0.001f;

    float b[KN], proj[KN];
    #pragma unroll
    for (int k = 0; k < KN; ++k) { b[k] = beta_in[k]; proj[k] = b[k]; }
    for (int it = 0; it < 100; ++it) {
        float v[KN];
        #pragma unroll
        for (int a2 = 0; a2 < KN; ++a2) {
            float qb = Q[a2][0] * b[0] + Q[a2][1] * b[1] + Q[a2][2] * b[2]
                     + Q[a2][3] * b[3] + Q[a2][4] * b[4];
            v[a2] = b[a2] - qb;
        }
        float mu0 = v[0], mu1 = v[1], mu2 = v[2], mu3 = v[3], mu4 = v[4];
#define CMPSW(x, y) { float hi_ = fmaxf(x, y); float lo_ = fminf(x, y); x = hi_; y = lo_; }
        CMPSW(mu0, mu1) CMPSW(mu3, mu4) CMPSW(mu2, mu4) CMPSW(mu2, mu3)
        CMPSW(mu0, mu3) CMPSW(mu0, mu2) CMPSW(mu1, mu4) CMPSW(mu1, mu3) CMPSW(mu1, mu2)
#undef CMPSW
        float cs0 = mu0, cs1 = cs0 + mu1, cs2 = cs1 + mu2, cs3 = cs2 + mu3, cs4 = cs3 + mu4;
        bool c1 = mu1 * 2.0f > cs1 - 1.0f;
        bool c2 = mu2 * 3.0f > cs2 - 1.0f;
        bool c3 = mu3 * 4.0f > cs3 - 1.0f;
        bool c4 = mu4 * 5.0f > cs4 - 1.0f;
        float csSel = cs0, rcpSel = 1.0f;
        if (c1) { csSel = cs1; rcpSel = 0.5f; }
        if (c2) { csSel = cs2; rcpSel = (1.0f / 3.0f); }
        if (c3) { csSel = cs3; rcpSel = 0.25f; }
        if (c4) { csSel = cs4; rcpSel = 0.2f; }
        float theta = (csSel - 1.0f) * rcpSel;
        float ssum = 0.0f;
        #pragma unroll
        for (int k = 0; k < KN; ++k) { proj[k] = fmaxf(v[k] - theta, 0.0f); ssum += proj[k]; }
        float invs = 1.0f / (ssum + 1e-12f);
        float nd = 0.0f;
        #pragma unroll
        for (int k = 0; k < KN; ++k) {
            proj[k] *= invs;
            float dd = proj[k] - b[k];
            nd += dd * dd;
            b[k] = proj[k];
        }
        if (nd < 1e-12f) break;
    }
    #pragma unroll
    for (int k = 0; k < KN; ++k) beta_out[k] = proj[k];
}

// ---------------------------------------------------------------- k_prep2 (r13 exact + cnt zero)
__global__ __launch_bounds__(256) void k_prep2(const float* __restrict__ S,
                                               const float* __restrict__ T,
                                               unsigned short* __restrict__ Hi,
                                               unsigned short* __restrict__ Lo,
                                               float* __restrict__ norms,
                                               float* __restrict__ g,
                                               unsigned* __restrict__ hists,
                                               unsigned* __restrict__ sel)
{
    if (blockIdx.x < 45) hists[blockIdx.x * 256 + threadIdx.x] = 0;  // 45*256=11520 (incl cnt)
    if (blockIdx.x == 50 && threadIdx.x == 0) {
        sel[0] = 0u; sel[1] = 8386559u;          // middle ranks of 4096*4095
        sel[2] = 0u; sel[3] = 8386560u;
        sel[4] = 0u;
    }
    int p = blockIdx.x * 4 + (threadIdx.x >> 6);
    int l = threadIdx.x & 63;
    const float* r0 = S + (size_t)(2 * p) * DDIM;
    const float* r1 = r0 + DDIM;
    const float* r2 = T + (size_t)(2 * p) * DDIM;
    const float* r3 = r2 + DDIM;
    float a[8], b[8], c[8], d[8];
    *(float4*)&a[0] = *(const float4*)(r0 + l * 8); *(float4*)&a[4] = *(const float4*)(r0 + l * 8 + 4);
    *(float4*)&b[0] = *(const float4*)(r1 + l * 8); *(float4*)&b[4] = *(const float4*)(r1 + l * 8 + 4);
    *(float4*)&c[0] = *(const float4*)(r2 + l * 8); *(float4*)&c[4] = *(const float4*)(r2 + l * 8 + 4);
    *(float4*)&d[0] = *(const float4*)(r3 + l * 8); *(float4*)&d[4] = *(const float4*)(r3 + l * 8 + 4);

    float n0 = 0, n1 = 0, n2 = 0, n3 = 0;
    float s01 = 0, s23 = 0, s02 = 0, s13 = 0, s03 = 0, s12 = 0;
    u16x8 h0, l0, h1, l1, h2, l2, h3, l3;
    #pragma unroll
    for (int k = 0; k < 8; ++k) {
        float va = a[k], vb = b[k], vc = c[k], vd = d[k];
        n0 += va * va; n1 += vb * vb; n2 += vc * vc; n3 += vd * vd;
        float t01 = va - vb, t23 = vc - vd, t02 = va - vc, t13 = vb - vd;
        s01 += t01*t01; s23 += t23*t23; s02 += t02*t02; s13 += t13*t13;
        float t03 = va - vd, t12 = vb - vc;
        s03 += t03*t03; s12 += t12*t12;
        unsigned short hh;
        hh = f2bf(va); h0[k] = hh; l0[k] = f2bf(va - bf2f(hh));
        hh = f2bf(vb); h1[k] = hh; l1[k] = f2bf(vb - bf2f(hh));
        hh = f2bf(vc); h2[k] = hh; l2[k] = f2bf(vc - bf2f(hh));
        hh = f2bf(vd); h3[k] = hh; l3[k] = f2bf(vd - bf2f(hh));
    }
    size_t g0 = (size_t)(2 * p) * DDIM + l * 8;
    size_t g1 = g0 + DDIM;
    size_t g2 = (size_t)(NS + 2 * p) * DDIM + l * 8;
    size_t g3 = g2 + DDIM;
    *(u16x8*)&Hi[g0] = h0; *(u16x8*)&Lo[g0] = l0;
    *(u16x8*)&Hi[g1] = h1; *(u16x8*)&Lo[g1] = l1;
    *(u16x8*)&Hi[g2] = h2; *(u16x8*)&Lo[g2] = l2;
    *(u16x8*)&Hi[g3] = h3; *(u16x8*)&Lo[g3] = l3;

    #pragma unroll
    for (int m = 32; m > 0; m >>= 1) {
        n0 += __shfl_xor(n0, m); n1 += __shfl_xor(n1, m);
        n2 += __shfl_xor(n2, m); n3 += __shfl_xor(n3, m);
        s01 += __shfl_xor(s01, m); s23 += __shfl_xor(s23, m);
        s02 += __shfl_xor(s02, m); s13 += __shfl_xor(s13, m);
        s03 += __shfl_xor(s03, m); s12 += __shfl_xor(s12, m);
    }
    if (l == 0) {
        norms[2 * p] = n0; norms[2 * p + 1] = n1;
        norms[NS + 2 * p] = n2; norms[NS + 2 * p + 1] = n3;
        float v[6] = { s01, s02, s03, s12, s13, s23 };
        for (int i = 0; i < 5; ++i)
            for (int j = 0; j < 5 - i; ++j)
                if (v[j] > v[j + 1]) { float t = v[j]; v[j] = v[j + 1]; v[j + 1] = t; }
        float med = 0.5f * (v[2] + v[3]);
        float bw = (med + 1e-6f) * 0.25f;
        #pragma unroll
        for (int k = 0; k < KN; ++k) {
            float inv = 1.0f / (bw * (float)(1 << k));
            g[(size_t)p * KN + k] = expf(-s01 * inv) + expf(-s23 * inv)
                                  - expf(-s02 * inv) - expf(-s13 * inv);
        }
    }
}

// ---------------------------------------------------------------- k_dist_mfma (r13 exact)
__global__ __launch_bounds__(256) void k_dist_mfma(const unsigned short* __restrict__ Hi,
                                                   const unsigned short* __restrict__ Lo,
                                                   const float* __restrict__ norms,
                                                   float* __restrict__ D,
                                                   const float* __restrict__ g,
                                                   const float* __restrict__ beta_in,
                                                   float* __restrict__ beta_out)
{
    __shared__ __align__(16) unsigned short sA[2][2][128][32];
    __shared__ __align__(16) unsigned short sB[2][2][128][32];

    if (blockIdx.x == 0) {
        if (threadIdx.x < 64) beta_solve(g, beta_in, beta_out);
        return;
    }

    int bx, by;
    tri_map(xcd_tile(blockIdx.x - 1), bx, by);
    const int m0 = by * 128, n0 = bx * 128;

    const int tid = threadIdx.x;
    const int w = tid >> 6, l = tid & 63;
    const int wr = w >> 1, wc = w & 1;

    const int chunk = (l & 3) ^ ((((l >> 2) & 3) + ((l >> 4) & 3)) & 3);
    const size_t gA0 = (size_t)(m0 + w * 16 + (l >> 2)) * DDIM + chunk * 8;
    const size_t gA1 = gA0 + (size_t)64 * DDIM;
    const size_t gB0 = (size_t)(n0 + w * 16 + (l >> 2)) * DDIM + chunk * 8;
    const size_t gB1 = gB0 + (size_t)64 * DDIM;
    const unsigned w1024 = w * 1024;

#define GLD(dst, srcptr, goff)                                                      \
    __builtin_amdgcn_global_load_lds(                                               \
        (const __attribute__((address_space(1))) unsigned*)((srcptr) + (goff)),     \
        (__attribute__((address_space(3))) unsigned*)((char*)(dst) + w1024), 16, 0, 0)
#define STAGE(buf, kk)                                  \
    do {                                                \
        GLD(&sA[buf][0][0][0],  Hi, gA0 + (kk));        \
        GLD(&sA[buf][0][64][0], Hi, gA1 + (kk));        \
        GLD(&sA[buf][1][0][0],  Lo, gA0 + (kk));        \
        GLD(&sA[buf][1][64][0], Lo, gA1 + (kk));        \
        GLD(&sB[buf][0][0][0],  Hi, gB0 + (kk));        \
        GLD(&sB[buf][0][64][0], Hi, gB1 + (kk));        \
        GLD(&sB[buf][1][0][0],  Lo, gB0 + (kk));        \
        GLD(&sB[buf][1][64][0], Lo, gB1 + (kk));        \
    } while (0)

    f32x4 acc[4][4] = {};
    const int q = l >> 4;
    const int fr = ((l & 3) + ((l >> 2) & 3)) & 3;
    const unsigned soff = ((unsigned)(q ^ fr)) << 4;
    const unsigned rowbA = (wr * 64 + (l & 15)) * 64 + soff;
    const unsigned rowbB = (wc * 64 + (l & 15)) * 64 + soff;

    STAGE(0, 0);
    __syncthreads();

    #pragma unroll 2
    for (int t = 0; t < 16; ++t) {
        const int cur = t & 1;
        if (t < 15) STAGE(cur ^ 1, (t + 1) * 32);

        bf16x8 ah[4], al[4], bh[4], bl[4];
        #pragma unroll
        for (int m = 0; m < 4; ++m) {
            ah[m] = *(const bf16x8*)((const char*)&sA[cur][0][0][0] + rowbA + m * 1024);
            al[m] = *(const bf16x8*)((const char*)&sA[cur][1][0][0] + rowbA + m * 1024);
        }
        #pragma unroll
        for (int n = 0; n < 4; ++n) {
            bh[n] = *(const bf16x8*)((const char*)&sB[cur][0][0][0] + rowbB + n * 1024);
            bl[n] = *(const bf16x8*)((const char*)&sB[cur][1][0][0] + rowbB + n * 1024);
        }
        #pragma unroll
        for (int m = 0; m < 4; ++m)
            #pragma unroll
            for (int n = 0; n < 4; ++n) {
                acc[m][n] = __builtin_amdgcn_mfma_f32_16x16x32_bf16(bh[n], ah[m], acc[m][n], 0, 0, 0);
                acc[m][n] = __builtin_amdgcn_mfma_f32_16x16x32_bf16(bl[n], ah[m], acc[m][n], 0, 0, 0);
                acc[m][n] = __builtin_amdgcn_mfma_f32_16x16x32_bf16(bh[n], al[m], acc[m][n], 0, 0, 0);
            }
        __syncthreads();
    }
#undef STAGE
#undef GLD

    float* ncache = (float*)&sB[0][0][0][0];
    if (tid < 128) ncache[tid] = norms[m0 + tid];
    else           ncache[tid] = norms[n0 + tid - 128];
    __syncthreads();

    float* rowbuf = (float*)&sA[0][0][0][0] + w * 1024;   // 16x64 floats per wave
    const int rr = l & 15;
    #pragma unroll
    for (int m = 0; m < 4; ++m) {
        float nrm = ncache[wr * 64 + m * 16 + rr];
        #pragma unroll
        for (int n = 0; n < 4; ++n) {
            float4 ncv = *(const float4*)&ncache[128 + wc * 64 + n * 16 + (q << 2)];
            f32x4 a = acc[m][n];
            float4 o;
            o.x = fmaxf(nrm + ncv.x - 2.0f * a[0], 0.0f);
            o.y = fmaxf(nrm + ncv.y - 2.0f * a[1], 0.0f);
            o.z = fmaxf(nrm + ncv.z - 2.0f * a[2], 0.0f);
            o.w = fmaxf(nrm + ncv.w - 2.0f * a[3], 0.0f);
            int ch = (n * 4 + q) ^ (rr & 7);
            *(float4*)(rowbuf + rr * 64 + ch * 4) = o;
        }
        #pragma unroll
        for (int s = 0; s < 4; ++s) {
            int row = s * 4 + q;
            int ch = (l & 15) ^ (row & 7);
            float4 v = *(const float4*)(rowbuf + row * 64 + ch * 4);
            *(float4*)&D[(size_t)(m0 + wr * 64 + m * 16 + row) * NT + n0 + wc * 64 + (l & 15) * 4] = v;
        }
    }
}

// ---------------------------------------------------------------- k_msel
// persistent: h0 -> s0 -> h1 -> s1 -> h2 -> s2 -> wsum -> final, one kernel.
// block 0 = scan block; blocks 1..528 own tile xcd_tile(b-1) (L2-resident
// across phases). All cross-block data via device atomics (XCD coherence).
__global__ __launch_bounds__(256) void k_msel(const float* __restrict__ D,
                                              unsigned* __restrict__ sel,
                                              unsigned* __restrict__ gH,
                                              unsigned* __restrict__ g1A,
                                              unsigned* __restrict__ g1B,
                                              unsigned* __restrict__ g2A,
                                              unsigned* __restrict__ g2B,
                                              unsigned* __restrict__ cnt,
                                              const float* __restrict__ beta,
                                              double* __restrict__ partials,
                                              float* __restrict__ out)
{
    __shared__ unsigned lds[8192];
    __shared__ double red[256];
    __shared__ unsigned tk;
    const int tid = threadIdx.x;
    const bool lead = (blockIdx.x == 0);
    int m0 = 0, n0 = 0;
    unsigned wt = 1;
    bool diagT = false;
    if (!lead) {
        int bx, by;
        tri_map(xcd_tile(blockIdx.x - 1), bx, by);
        m0 = by * 128; n0 = bx * 128;
        wt = (bx != by) ? 2u : 1u;
        diagT = (bx == by);
    }
    (void)diagT;

#define ARRIVE(K) do { __threadfence(); __syncthreads(); \
        if (tid == 0) atomicAdd(&cnt[K], 1u); } while (0)
#define WAITFOR(K, VAL) do { if (tid == 0) { unsigned it_ = 0; \
        while (atomicAdd(&cnt[K], 0u) < (VAL)) { \
            __builtin_amdgcn_s_sleep(8); if (++it_ > 100000000u) break; } } \
        __syncthreads(); } while (0)

    // ================= phase H0: 10-bit hist (key>>22)
    if (!lead) {
        for (int i = tid; i < 1024; i += 256) lds[i] = 0;
        __syncthreads();
        #pragma unroll
        for (int i = 0; i < 16; ++i) {
            int v = tid + 256 * i;
            int r = m0 + (v >> 5), c0 = n0 + (v & 31) * 4;
            float4 dv = *(const float4*)&D[(size_t)r * NT + c0];
            const float* dd = (const float*)&dv;
            unsigned pb = __float_as_uint(dd[0]) >> 22;
            unsigned pc = (r == c0) ? 0u : wt;
            #pragma unroll
            for (int j = 1; j < 4; ++j) {
                unsigned bj = __float_as_uint(dd[j]) >> 22;
                unsigned cj = (r == c0 + j) ? 0u : wt;
                if (bj == pb) pc += cj;
                else { if (pc) atomicAdd(&lds[pb], pc); pb = bj; pc = cj; }
            }
            if (pc) atomicAdd(&lds[pb], pc);
        }
        __syncthreads();
        for (int i = tid; i < 1024; i += 256) {
            unsigned c = lds[i];
            if (c) atomicAdd(&gH[i], c);
        }
    }
    ARRIVE(0);
    if (lead) {
        WAITFOR(0, NBLK);
        // stage + scan0 (both targets share gH)
        for (int i = tid; i < 1024; i += 256) lds[i] = aload(&gH[i]);
        __syncthreads();
        if (tid < 64) {
            unsigned bA, rA, bB, rB;
            wscan(lds, 16, 8386559u, bA, rA);
            wscan(lds, 16, 8386560u, bB, rB);
            if (tid == 0) {
                atomicExch(&sel[0], bA); atomicExch(&sel[1], rA);
                atomicExch(&sel[2], bB); atomicExch(&sel[3], rB);
            }
        }
        __threadfence();
        __syncthreads();
        if (tid == 0) atomicAdd(&cnt[0], 1u);   // release
    } else {
        WAITFOR(0, NBLK + 1);
    }

    // ================= phase H1: 10-bit hist ((key>>12)&1023) restricted
    if (!lead) {
        unsigned pA, pB;
        if (tid == 0) { lds[8190] = aload(&sel[0]); lds[8191] = aload(&sel[2]); }
        for (int i = tid; i < 2048; i += 256) lds[i] = 0;
        __syncthreads();
        pA = lds[8190]; pB = lds[8191];
        #pragma unroll
        for (int i = 0; i < 16; ++i) {
            int v = tid + 256 * i;
            int r = m0 + (v >> 5), c0 = n0 + (v & 31) * 4;
            float4 dv = *(const float4*)&D[(size_t)r * NT + c0];
            const float* dd = (const float*)&dv;
            #pragma unroll
            for (int j = 0; j < 4; ++j) {
                if (r == c0 + j) continue;
                unsigned key = __float_as_uint(dd[j]);
                if ((key >> 22) == pA) atomicAdd(&lds[(key >> 12) & 1023], wt);
                if ((key >> 22) == pB) atomicAdd(&lds[1024 + ((key >> 12) & 1023)], wt);
            }
        }
        __syncthreads();
        for (int i = tid; i < 1024; i += 256) {
            unsigned ca = lds[i];
            if (ca) atomicAdd(&g1A[i], ca);
            unsigned cb = lds[1024 + i];
            if (cb) atomicAdd(&g1B[i], cb);
        }
    }
    ARRIVE(1);
    if (lead) {
        WAITFOR(1, NBLK);
        for (int i = tid; i < 1024; i += 256) {
            lds[i] = aload(&g1A[i]);
            lds[1024 + i] = aload(&g1B[i]);
        }
        __syncthreads();
        if (tid < 64) {
            unsigned pA = aload(&sel[0]), rkA = aload(&sel[1]);
            unsigned pB = aload(&sel[2]), rkB = aload(&sel[3]);
            unsigned bA, rA, bB, rB;
            wscan(lds, 16, rkA, bA, rA);
            wscan(lds + 1024, 16, rkB, bB, rB);
            if (tid == 0) {
                atomicExch(&sel[0], (pA << 10) | bA); atomicExch(&sel[1], rA);
                atomicExch(&sel[2], (pB << 10) | bB); atomicExch(&sel[3], rB);
            }
        }
        __threadfence();
        __syncthreads();
        if (tid == 0) atomicAdd(&cnt[1], 1u);
    } else {
        WAITFOR(1, NBLK + 1);
    }

    // ================= phase H2: 12-bit hist (key&4095) restricted (key>>12 prefix)
    if (!lead) {
        unsigned pA, pB;
        if (tid == 0) { unsigned a = aload(&sel[0]), b = aload(&sel[2]); lds[0] = a; lds[1] = b; }
        __syncthreads();
        pA = lds[0]; pB = lds[1];
        __syncthreads();
        for (int i = tid; i < 8192; i += 256) lds[i] = 0;
        __syncthreads();
        #pragma unroll
        for (int i = 0; i < 16; ++i) {
            int v = tid + 256 * i;
            int r = m0 + (v >> 5), c0 = n0 + (v & 31) * 4;
            float4 dv = *(const float4*)&D[(size_t)r * NT + c0];
            const float* dd = (const float*)&dv;
            #pragma unroll
            for (int j = 0; j < 4; ++j) {
                if (r == c0 + j) continue;
                unsigned key = __float_as_uint(dd[j]);
                if ((key >> 12) == pA) atomicAdd(&lds[key & 4095], wt);
                if ((key >> 12) == pB) atomicAdd(&lds[4096 + (key & 4095)], wt);
            }
        }
        __syncthreads();
        for (int i = tid; i < 4096; i += 256) {
            unsigned ca = lds[i];
            if (ca) atomicAdd(&g2A[i], ca);
            unsigned cb = lds[4096 + i];
            if (cb) atomicAdd(&g2B[i], cb);
        }
    }
    ARRIVE(2);
    if (lead) {
        WAITFOR(2, NBLK);
        for (int i = tid; i < 4096; i += 256) {
            lds[i] = aload(&g2A[i]);
            lds[4096 + i] = aload(&g2B[i]);
        }
        __syncthreads();
        if (tid < 64) {
            unsigned pA = aload(&sel[0]), rkA = aload(&sel[1]);
            unsigned pB = aload(&sel[2]), rkB = aload(&sel[3]);
            unsigned bA, rA, bB, rB;
            wscan(lds, 64, rkA, bA, rA);
            wscan(lds + 4096, 64, rkB, bB, rB);
            if (tid == 0) {
                unsigned keyA = (pA << 12) | bA;
                unsigned keyB = (pB << 12) | bB;
                float med = 0.5f * (__uint_as_float(keyA) + __uint_as_float(keyB));
                float bw = (med + 1e-6f) * 0.25f;
                float i4 = 1.0f / (bw * 16.0f);
                atomicExch(&sel[4], __float_as_uint(i4));
            }
        }
        __threadfence();
        __syncthreads();
        if (tid == 0) atomicAdd(&cnt[2], 1u);
        return;                                   // block 0 done
    } else {
        WAITFOR(2, NBLK + 1);
    }

    // ================= phase WSUM + ticket final (workers only)
    {
        if (tid == 0) lds[0] = aload(&sel[4]);
        __syncthreads();
        float i4 = __uint_as_float(lds[0]);
        float b0 = beta[0], b1 = beta[1], b2 = beta[2], b3 = beta[3], b4 = beta[4];
        const double wDiag = 1.0 / ((double)NS * (NS - 1));
        const double wOff = -1.0 / ((double)NS * NS);
        double wtd = (wt == 2u) ? 2.0 : 1.0;
        double acc = 0.0;
        #pragma unroll
        for (int i = 0; i < 16; ++i) {
            int v = tid + 256 * i;
            int r = m0 + (v >> 5), c0 = n0 + (v & 31) * 4;
            float4 dv = *(const float4*)&D[(size_t)r * NT + c0];
            const float* dd = (const float*)&dv;
            #pragma unroll
            for (int j = 0; j < 4; ++j) {
                int c = c0 + j;
                if (r == c) continue;
                float sq = dd[j];
                float y1 = __expf(-sq * i4);
                float y2 = y1 * y1;
                float y4 = y2 * y2;
                float y8 = y4 * y4;
                float y16 = y8 * y8;
                float val = b4 * y1 + b3 * y2 + b2 * y4 + b1 * y8 + b0 * y16;
                bool same = (r < NS) == (c < NS);
                acc += (same ? wDiag : wOff) * (double)val;
            }
        }
        acc *= wtd;
        red[tid] = acc;
        __syncthreads();
        for (int off = 128; off > 0; off >>= 1) {
            if (tid < off) red[tid] += red[tid + off];
            __syncthreads();
        }
        if (tid == 0) {
            partials[blockIdx.x - 1] = red[0];
            __threadfence();
            tk = atomicAdd(&cnt[3], 1u);
        }
        __syncthreads();
        if (tk == NTILES - 1) {
            __threadfence();
            double a2 = 0.0;
            for (int i = tid; i < NTILES; i += 256) {
                unsigned long long u = atomicAdd((unsigned long long*)&partials[i], 0ull);
                a2 += __longlong_as_double(u);
            }
            red[tid] = a2;
            __syncthreads();
            for (int off = 128; off > 0; off >>= 1) {
                if (tid < off) red[tid] += red[tid + off];
                __syncthreads();
            }
            if (tid == 0) out[0] = (float)fmax(red[0], 0.0);
        }
    }
#undef ARRIVE
#undef WAITFOR
}

// ---------------------------------------------------------------- launch
extern "C" void kernel_launch(void* const* d_in, const int* in_sizes, int n_in,
                              void* d_out, int out_size, void* d_ws, size_t ws_size,
                              hipStream_t stream)
{
    const float* S = (const float*)d_in[0];
    const float* T = (const float*)d_in[1];
    const float* beta = (const float*)d_in[2];
    float* out = (float*)d_out;

    float* D = (float*)d_ws;                              // 4096*4096 f
    unsigned short* Hi = (unsigned short*)(D + (size_t)NT * NT);
    unsigned short* Lo = Hi + (size_t)NT * DDIM;
    float* norms = (float*)(Lo + (size_t)NT * DDIM);      // 4096 f
    float* g = norms + NT;                                // 5120 f
    float* beta2 = g + 1024 * KN;                         // 8 f
    unsigned* sel = (unsigned*)(beta2 + 8);               // 16 u
    unsigned* hists = sel + 16;                           // 11520 u (incl cnt)
    unsigned* gH  = hists;                                // 1024
    unsigned* g1A = hists + 1024;                         // 1024
    unsigned* g1B = hists + 2048;                         // 1024
    unsigned* g2A = hists + 3072;                         // 4096
    unsigned* g2B = hists + 7168;                         // 4096
    unsigned* cnt = hists + 11264;                        // 8
    double* partials = (double*)(hists + 11520);          // 528 d

    k_prep2<<<dim3(256), dim3(256), 0, stream>>>(S, T, Hi, Lo, norms, g, hists, sel);
    k_dist_mfma<<<dim3(NTILES + 1), dim3(256), 0, stream>>>(Hi, Lo, norms, D, g, beta, beta2);
    k_msel<<<dim3(NBLK), dim3(256), 0, stream>>>(D, sel, gH, g1A, g1B, g2A, g2B,
                                                 cnt, beta2, partials, out);
}

// Round 17
// 144.319 us; speedup vs baseline: 2.2116x; 2.2116x over previous
//
#include <hip/hip_runtime.h>
#include <math.h>

#define NT 4096
#define NS 2048
#define DDIM 512
#define KN 5
#define NTILES 528   // 32*33/2 triangle tiles of 128x128

typedef __bf16 bf16x8 __attribute__((ext_vector_type(8)));
typedef float f32x4 __attribute__((ext_vector_type(4)));
typedef unsigned short u16x8 __attribute__((ext_vector_type(8)));

static __device__ inline unsigned short f2bf(float x) {
    unsigned u = __float_as_uint(x);
    unsigned r = (u + 0x7fffu + ((u >> 16) & 1u)) >> 16;
    return (unsigned short)r;
}
static __device__ inline float bf2f(unsigned short h) {
    return __uint_as_float(((unsigned)h) << 16);
}

static __device__ inline void tri_map(int b, int& bx, int& by) {
    int x = (int)((sqrtf(8.0f * (float)b + 1.0f) - 1.0f) * 0.5f);
    while ((x + 1) * (x + 2) / 2 <= b) ++x;
    while (x * (x + 1) / 2 > b) --x;
    bx = x;
    by = b - x * (x + 1) / 2;
}

// dist writes tile swz(i-1) from block i; all D-readers use the SAME mapping
// (grid NTILES+1, block 0 idle) so reader XCD == writer XCD -> L2 hits.
static __device__ inline int xcd_tile(int bb) {
    return (bb & 7) * 66 + (bb >> 3);            // 528 = 8*66, bijective
}

// ---------------------------------------------------------------- beta solve
static __device__ void beta_solve(const float* __restrict__ g,
                                  const float* __restrict__ beta_in,
                                  float* __restrict__ beta_out)
{
    int lane = threadIdx.x;
    float gs[KN] = {0, 0, 0, 0, 0};
    float gg[15];
    #pragma unroll
    for (int i = 0; i < 15; ++i) gg[i] = 0.0f;
    for (int p = lane; p < 1024; p += 64) {
        float gv[KN];
        #pragma unroll
        for (int k = 0; k < KN; ++k) gv[k] = g[(size_t)p * KN + k];
        int idx = 0;
        #pragma unroll
        for (int a2 = 0; a2 < KN; ++a2) {
            gs[a2] += gv[a2];
            #pragma unroll
            for (int b2 = a2; b2 < KN; ++b2) gg[idx++] += gv[a2] * gv[b2];
        }
    }
    #pragma unroll
    for (int m = 32; m > 0; m >>= 1) {
        #pragma unroll
        for (int k = 0; k < KN; ++k) gs[k] += __shfl_xor(gs[k], m);
        #pragma unroll
        for (int i = 0; i < 15; ++i) gg[i] += __shfl_xor(gg[i], m);
    }
    if (lane != 0) return;

    float Q[KN][KN], gm[KN];
    #pragma unroll
    for (int k = 0; k < KN; ++k) gm[k] = gs[k] * (1.0f / 1024.0f);
    int idx = 0;
    #pragma unroll
    for (int a2 = 0; a2 < KN; ++a2)
        #pragma unroll
        for (int b2 = a2; b2 < KN; ++b2) {
            float qv = gg[idx++] * (1.0f / 1024.0f) - gm[a2] * gm[b2];
            Q[a2][b2] = qv; Q[b2][a2] = qv;
        }
    #pragma unroll
    for (int k = 0; k < KN; ++k) Q[k][k] += 0.001f;

    float b[KN], proj[KN];
    #pragma unroll
    for (int k = 0; k < KN; ++k) { b[k] = beta_in[k]; proj[k] = b[k]; }
    for (int it = 0; it < 100; ++it) {
        float v[KN];
        #pragma unroll
        for (int a2 = 0; a2 < KN; ++a2) {
            float qb = Q[a2][0] * b[0] + Q[a2][1] * b[1] + Q[a2][2] * b[2]
                     + Q[a2][3] * b[3] + Q[a2][4] * b[4];
            v[a2] = b[a2] - qb;
        }
        float mu0 = v[0], mu1 = v[1], mu2 = v[2], mu3 = v[3], mu4 = v[4];
#define CMPSW(x, y) { float hi_ = fmaxf(x, y); float lo_ = fminf(x, y); x = hi_; y = lo_; }
        CMPSW(mu0, mu1) CMPSW(mu3, mu4) CMPSW(mu2, mu4) CMPSW(mu2, mu3)
        CMPSW(mu0, mu3) CMPSW(mu0, mu2) CMPSW(mu1, mu4) CMPSW(mu1, mu3) CMPSW(mu1, mu2)
#undef CMPSW
        float cs0 = mu0, cs1 = cs0 + mu1, cs2 = cs1 + mu2, cs3 = cs2 + mu3, cs4 = cs3 + mu4;
        bool c1 = mu1 * 2.0f > cs1 - 1.0f;
        bool c2 = mu2 * 3.0f > cs2 - 1.0f;
        bool c3 = mu3 * 4.0f > cs3 - 1.0f;
        bool c4 = mu4 * 5.0f > cs4 - 1.0f;
        float csSel = cs0, rcpSel = 1.0f;
        if (c1) { csSel = cs1; rcpSel = 0.5f; }
        if (c2) { csSel = cs2; rcpSel = (1.0f / 3.0f); }
        if (c3) { csSel = cs3; rcpSel = 0.25f; }
        if (c4) { csSel = cs4; rcpSel = 0.2f; }
        float theta = (csSel - 1.0f) * rcpSel;
        float ssum = 0.0f;
        #pragma unroll
        for (int k = 0; k < KN; ++k) { proj[k] = fmaxf(v[k] - theta, 0.0f); ssum += proj[k]; }
        float invs = 1.0f / (ssum + 1e-12f);
        float nd = 0.0f;
        #pragma unroll
        for (int k = 0; k < KN; ++k) {
            proj[k] *= invs;
            float dd = proj[k] - b[k];
            nd += dd * dd;
            b[k] = proj[k];
        }
        if (nd < 1e-12f) break;
    }
    #pragma unroll
    for (int k = 0; k < KN; ++k) beta_out[k] = proj[k];
}

// ---------------------------------------------------------------- k_prep2
__global__ __launch_bounds__(256) void k_prep2(const float* __restrict__ S,
                                               const float* __restrict__ T,
                                               unsigned short* __restrict__ Hi,
                                               unsigned short* __restrict__ Lo,
                                               float* __restrict__ norms,
                                               float* __restrict__ g,
                                               unsigned* __restrict__ hists,
                                               unsigned* __restrict__ sel)
{
    if (blockIdx.x < 44) hists[blockIdx.x * 256 + threadIdx.x] = 0;  // 44*256=11264
    if (blockIdx.x == 50 && threadIdx.x == 0) {
        sel[0] = 0u; sel[1] = 8386559u;          // middle ranks of 4096*4095
        sel[2] = 0u; sel[3] = 8386560u;
    }
    int p = blockIdx.x * 4 + (threadIdx.x >> 6);
    int l = threadIdx.x & 63;
    const float* r0 = S + (size_t)(2 * p) * DDIM;
    const float* r1 = r0 + DDIM;
    const float* r2 = T + (size_t)(2 * p) * DDIM;
    const float* r3 = r2 + DDIM;
    float a[8], b[8], c[8], d[8];
    *(float4*)&a[0] = *(const float4*)(r0 + l * 8); *(float4*)&a[4] = *(const float4*)(r0 + l * 8 + 4);
    *(float4*)&b[0] = *(const float4*)(r1 + l * 8); *(float4*)&b[4] = *(const float4*)(r1 + l * 8 + 4);
    *(float4*)&c[0] = *(const float4*)(r2 + l * 8); *(float4*)&c[4] = *(const float4*)(r2 + l * 8 + 4);
    *(float4*)&d[0] = *(const float4*)(r3 + l * 8); *(float4*)&d[4] = *(const float4*)(r3 + l * 8 + 4);

    float n0 = 0, n1 = 0, n2 = 0, n3 = 0;
    float s01 = 0, s23 = 0, s02 = 0, s13 = 0, s03 = 0, s12 = 0;
    u16x8 h0, l0, h1, l1, h2, l2, h3, l3;
    #pragma unroll
    for (int k = 0; k < 8; ++k) {
        float va = a[k], vb = b[k], vc = c[k], vd = d[k];
        n0 += va * va; n1 += vb * vb; n2 += vc * vc; n3 += vd * vd;
        float t01 = va - vb, t23 = vc - vd, t02 = va - vc, t13 = vb - vd;
        s01 += t01*t01; s23 += t23*t23; s02 += t02*t02; s13 += t13*t13;
        float t03 = va - vd, t12 = vb - vc;
        s03 += t03*t03; s12 += t12*t12;
        unsigned short hh;
        hh = f2bf(va); h0[k] = hh; l0[k] = f2bf(va - bf2f(hh));
        hh = f2bf(vb); h1[k] = hh; l1[k] = f2bf(vb - bf2f(hh));
        hh = f2bf(vc); h2[k] = hh; l2[k] = f2bf(vc - bf2f(hh));
        hh = f2bf(vd); h3[k] = hh; l3[k] = f2bf(vd - bf2f(hh));
    }
    size_t g0 = (size_t)(2 * p) * DDIM + l * 8;
    size_t g1 = g0 + DDIM;
    size_t g2 = (size_t)(NS + 2 * p) * DDIM + l * 8;
    size_t g3 = g2 + DDIM;
    *(u16x8*)&Hi[g0] = h0; *(u16x8*)&Lo[g0] = l0;
    *(u16x8*)&Hi[g1] = h1; *(u16x8*)&Lo[g1] = l1;
    *(u16x8*)&Hi[g2] = h2; *(u16x8*)&Lo[g2] = l2;
    *(u16x8*)&Hi[g3] = h3; *(u16x8*)&Lo[g3] = l3;

    #pragma unroll
    for (int m = 32; m > 0; m >>= 1) {
        n0 += __shfl_xor(n0, m); n1 += __shfl_xor(n1, m);
        n2 += __shfl_xor(n2, m); n3 += __shfl_xor(n3, m);
        s01 += __shfl_xor(s01, m); s23 += __shfl_xor(s23, m);
        s02 += __shfl_xor(s02, m); s13 += __shfl_xor(s13, m);
        s03 += __shfl_xor(s03, m); s12 += __shfl_xor(s12, m);
    }
    if (l == 0) {
        norms[2 * p] = n0; norms[2 * p + 1] = n1;
        norms[NS + 2 * p] = n2; norms[NS + 2 * p + 1] = n3;
        float v[6] = { s01, s02, s03, s12, s13, s23 };
        for (int i = 0; i < 5; ++i)
            for (int j = 0; j < 5 - i; ++j)
                if (v[j] > v[j + 1]) { float t = v[j]; v[j] = v[j + 1]; v[j + 1] = t; }
        float med = 0.5f * (v[2] + v[3]);
        float bw = (med + 1e-6f) * 0.25f;
        #pragma unroll
        for (int k = 0; k < KN; ++k) {
            float inv = 1.0f / (bw * (float)(1 << k));
            g[(size_t)p * KN + k] = expf(-s01 * inv) + expf(-s23 * inv)
                                  - expf(-s02 * inv) - expf(-s13 * inv);
        }
    }
}

// ---------------------------------------------------------------- k_dist_mfma (round-5 proven core)
__global__ __launch_bounds__(256) void k_dist_mfma(const unsigned short* __restrict__ Hi,
                                                   const unsigned short* __restrict__ Lo,
                                                   const float* __restrict__ norms,
                                                   float* __restrict__ D,
                                                   const float* __restrict__ g,
                                                   const float* __restrict__ beta_in,
                                                   float* __restrict__ beta_out)
{
    __shared__ __align__(16) unsigned short sA[2][2][128][32];
    __shared__ __align__(16) unsigned short sB[2][2][128][32];

    if (blockIdx.x == 0) {
        if (threadIdx.x < 64) beta_solve(g, beta_in, beta_out);
        return;
    }

    int bx, by;
    tri_map(xcd_tile(blockIdx.x - 1), bx, by);
    const int m0 = by * 128, n0 = bx * 128;

    const int tid = threadIdx.x;
    const int w = tid >> 6, l = tid & 63;
    const int wr = w >> 1, wc = w & 1;

    const int chunk = (l & 3) ^ ((((l >> 2) & 3) + ((l >> 4) & 3)) & 3);
    const size_t gA0 = (size_t)(m0 + w * 16 + (l >> 2)) * DDIM + chunk * 8;
    const size_t gA1 = gA0 + (size_t)64 * DDIM;
    const size_t gB0 = (size_t)(n0 + w * 16 + (l >> 2)) * DDIM + chunk * 8;
    const size_t gB1 = gB0 + (size_t)64 * DDIM;
    const unsigned w1024 = w * 1024;

#define GLD(dst, srcptr, goff)                                                      \
    __builtin_amdgcn_global_load_lds(                                               \
        (const __attribute__((address_space(1))) unsigned*)((srcptr) + (goff)),     \
        (__attribute__((address_space(3))) unsigned*)((char*)(dst) + w1024), 16, 0, 0)
#define STAGE(buf, kk)                                  \
    do {                                                \
        GLD(&sA[buf][0][0][0],  Hi, gA0 + (kk));        \
        GLD(&sA[buf][0][64][0], Hi, gA1 + (kk));        \
        GLD(&sA[buf][1][0][0],  Lo, gA0 + (kk));        \
        GLD(&sA[buf][1][64][0], Lo, gA1 + (kk));        \
        GLD(&sB[buf][0][0][0],  Hi, gB0 + (kk));        \
        GLD(&sB[buf][0][64][0], Hi, gB1 + (kk));        \
        GLD(&sB[buf][1][0][0],  Lo, gB0 + (kk));        \
        GLD(&sB[buf][1][64][0], Lo, gB1 + (kk));        \
    } while (0)

    f32x4 acc[4][4] = {};
    const int q = l >> 4;
    const int fr = ((l & 3) + ((l >> 2) & 3)) & 3;
    const unsigned soff = ((unsigned)(q ^ fr)) << 4;
    const unsigned rowbA = (wr * 64 + (l & 15)) * 64 + soff;
    const unsigned rowbB = (wc * 64 + (l & 15)) * 64 + soff;

    STAGE(0, 0);
    __syncthreads();

    #pragma unroll 2
    for (int t = 0; t < 16; ++t) {
        const int cur = t & 1;
        if (t < 15) STAGE(cur ^ 1, (t + 1) * 32);

        bf16x8 ah[4], al[4], bh[4], bl[4];
        #pragma unroll
        for (int m = 0; m < 4; ++m) {
            ah[m] = *(const bf16x8*)((const char*)&sA[cur][0][0][0] + rowbA + m * 1024);
            al[m] = *(const bf16x8*)((const char*)&sA[cur][1][0][0] + rowbA + m * 1024);
        }
        #pragma unroll
        for (int n = 0; n < 4; ++n) {
            bh[n] = *(const bf16x8*)((const char*)&sB[cur][0][0][0] + rowbB + n * 1024);
            bl[n] = *(const bf16x8*)((const char*)&sB[cur][1][0][0] + rowbB + n * 1024);
        }
        #pragma unroll
        for (int m = 0; m < 4; ++m)
            #pragma unroll
            for (int n = 0; n < 4; ++n) {
                acc[m][n] = __builtin_amdgcn_mfma_f32_16x16x32_bf16(bh[n], ah[m], acc[m][n], 0, 0, 0);
                acc[m][n] = __builtin_amdgcn_mfma_f32_16x16x32_bf16(bl[n], ah[m], acc[m][n], 0, 0, 0);
                acc[m][n] = __builtin_amdgcn_mfma_f32_16x16x32_bf16(bh[n], al[m], acc[m][n], 0, 0, 0);
            }
        __syncthreads();
    }
#undef STAGE
#undef GLD

    float* ncache = (float*)&sB[0][0][0][0];
    if (tid < 128) ncache[tid] = norms[m0 + tid];
    else           ncache[tid] = norms[n0 + tid - 128];
    __syncthreads();

    float* rowbuf = (float*)&sA[0][0][0][0] + w * 1024;   // 16x64 floats per wave
    const int rr = l & 15;
    #pragma unroll
    for (int m = 0; m < 4; ++m) {
        float nrm = ncache[wr * 64 + m * 16 + rr];
        #pragma unroll
        for (int n = 0; n < 4; ++n) {
            float4 ncv = *(const float4*)&ncache[128 + wc * 64 + n * 16 + (q << 2)];
            f32x4 a = acc[m][n];
            float4 o;
            o.x = fmaxf(nrm + ncv.x - 2.0f * a[0], 0.0f);
            o.y = fmaxf(nrm + ncv.y - 2.0f * a[1], 0.0f);
            o.z = fmaxf(nrm + ncv.z - 2.0f * a[2], 0.0f);
            o.w = fmaxf(nrm + ncv.w - 2.0f * a[3], 0.0f);
            int ch = (n * 4 + q) ^ (rr & 7);
            *(float4*)(rowbuf + rr * 64 + ch * 4) = o;
        }
        #pragma unroll
        for (int s = 0; s < 4; ++s) {
            int row = s * 4 + q;
            int ch = (l & 15) ^ (row & 7);
            float4 v = *(const float4*)(rowbuf + row * 64 + ch * 4);
            *(float4*)&D[(size_t)(m0 + wr * 64 + m * 16 + row) * NT + n0 + wc * 64 + (l & 15) * 4] = v;
        }
    }
}

// ---------------------------------------------------------------- k_hist0_tri (XCD-matched)
__global__ __launch_bounds__(256) void k_hist0_tri(const float* __restrict__ D,
                                                   unsigned* __restrict__ gH)
{
    if (blockIdx.x == 0) return;
    __shared__ unsigned h[1024];
    for (int i = threadIdx.x; i < 1024; i += 256) h[i] = 0;
    int bx, by;
    tri_map(xcd_tile(blockIdx.x - 1), bx, by);
    int m0 = by * 128, n0 = bx * 128;
    unsigned wt = (bx != by) ? 2u : 1u;
    __syncthreads();
    for (int v = threadIdx.x; v < 4096; v += 256) {
        int r = m0 + (v >> 5);
        int c0 = n0 + (v & 31) * 4;
        float4 dv = *(const float4*)&D[(size_t)r * NT + c0];
        const float* dd = (const float*)&dv;
        unsigned pb = __float_as_uint(dd[0]) >> 22;
        unsigned pc = (r == c0) ? 0u : wt;
        #pragma unroll
        for (int j = 1; j < 4; ++j) {
            unsigned bj = __float_as_uint(dd[j]) >> 22;
            unsigned cj = (r == c0 + j) ? 0u : wt;
            if (bj == pb) pc += cj;
            else {
                if (pc) atomicAdd(&h[pb], pc);
                pb = bj; pc = cj;
            }
        }
        if (pc) atomicAdd(&h[pb], pc);
    }
    __syncthreads();
    for (int i = threadIdx.x; i < 1024; i += 256) {
        unsigned c = h[i];
        if (c) atomicAdd(&gH[i], c);
    }
}

// ---------------------------------------------------------------- k_scan0
__global__ __launch_bounds__(64) void k_scan0(const unsigned* __restrict__ hL0,
                                              unsigned* __restrict__ sel)
{
    int lane = threadIdx.x;
    for (int t = 0; t < 2; ++t) {
        unsigned r = sel[t * 2 + 1];
        unsigned s = 0;
        for (int i = 0; i < 16; ++i) s += hL0[lane * 16 + i];
        unsigned x = s;
        #pragma unroll
        for (int off = 1; off < 64; off <<= 1) {
            unsigned y = __shfl_up(x, off);
            if (lane >= off) x += y;
        }
        unsigned base = x - s;
        bool has = (r >= base) && (r < base + s);
        unsigned long long mm = __ballot(has);
        int leader = __ffsll(mm) - 1;
        unsigned bin = 0, cb = 0;
        if (lane == leader) {
            unsigned cc = base;
            for (int i = 0; i < 16; ++i) {
                unsigned hv = hL0[lane * 16 + i];
                if (r < cc + hv) { bin = lane * 16 + i; cb = cc; break; }
                cc += hv;
            }
        }
        bin = __shfl(bin, leader);
        cb = __shfl(cb, leader);
        if (lane == 0) {
            sel[t * 2 + 0] = bin;
            sel[t * 2 + 1] = r - cb;
        }
    }
}

// ---------------------------------------------------------------- k_hist_tri (levels 1,2; XCD-matched)
template<int LEVEL>
__global__ __launch_bounds__(256) void k_hist_tri(const float* __restrict__ D,
                                                  const unsigned* __restrict__ sel,
                                                  unsigned* __restrict__ gA,
                                                  unsigned* __restrict__ gB)
{
    if (blockIdx.x == 0) return;
    constexpr int NB = (LEVEL == 2) ? 4096 : 1024;
    __shared__ unsigned lha[NB];
    __shared__ unsigned lhb[NB];
    for (int i = threadIdx.x; i < NB; i += 256) { lha[i] = 0; lhb[i] = 0; }
    unsigned pA = sel[0], pB = sel[2];
    int bx, by;
    tri_map(xcd_tile(blockIdx.x - 1), bx, by);
    int m0 = by * 128, n0 = bx * 128;
    unsigned wt = (bx != by) ? 2u : 1u;
    __syncthreads();
    for (int v = threadIdx.x; v < 4096; v += 256) {
        int r = m0 + (v >> 5);
        int c0 = n0 + (v & 31) * 4;
        float4 dv = *(const float4*)&D[(size_t)r * NT + c0];
        const float* dd = (const float*)&dv;
        #pragma unroll
        for (int j = 0; j < 4; ++j) {
            if (r == c0 + j) continue;
            unsigned key = __float_as_uint(dd[j]);
            if constexpr (LEVEL == 1) {
                if ((key >> 22) == pA) atomicAdd(&lha[(key >> 12) & 1023], wt);
                if ((key >> 22) == pB) atomicAdd(&lhb[(key >> 12) & 1023], wt);
            } else {
                if ((key >> 12) == pA) atomicAdd(&lha[key & 4095], wt);
                if ((key >> 12) == pB) atomicAdd(&lhb[key & 4095], wt);
            }
        }
    }
    __syncthreads();
    for (int i = threadIdx.x; i < NB; i += 256) {
        unsigned ca = lha[i];
        if (ca) atomicAdd(&gA[i], ca);
        unsigned cb = lhb[i];
        if (cb) atomicAdd(&gB[i], cb);
    }
}

// ---------------------------------------------------------------- k_scan (levels 1,2)
template<int LEVEL>
__global__ __launch_bounds__(64) void k_scan(const unsigned* __restrict__ hA,
                                             const unsigned* __restrict__ hB,
                                             unsigned* __restrict__ sel,
                                             float* __restrict__ params)
{
    constexpr int NB = (LEVEL == 2) ? 4096 : 1024;
    constexpr int C = NB / 64;
    int lane = threadIdx.x;
    for (int t = 0; t < 2; ++t) {
        const unsigned* h = (t == 0 ? hA : hB);
        unsigned r = sel[t * 2 + 1];
        unsigned s = 0;
        for (int i = 0; i < C; ++i) s += h[lane * C + i];
        unsigned x = s;
        #pragma unroll
        for (int off = 1; off < 64; off <<= 1) {
            unsigned y = __shfl_up(x, off);
            if (lane >= off) x += y;
        }
        unsigned base = x - s;
        bool has = (r >= base) && (r < base + s);
        unsigned long long mm = __ballot(has);
        int leader = __ffsll(mm) - 1;
        unsigned bin = 0, cb = 0;
        if (lane == leader) {
            unsigned cc = base;
            for (int i = 0; i < C; ++i) {
                unsigned hv = h[lane * C + i];
                if (r < cc + hv) { bin = lane * C + i; cb = cc; break; }
                cc += hv;
            }
        }
        bin = __shfl(bin, leader);
        cb = __shfl(cb, leader);
        if (lane == 0) {
            if (LEVEL == 1) sel[t * 2 + 0] = (sel[t * 2 + 0] << 10) | bin;
            else            sel[4 + t]     = (sel[t * 2 + 0] << 12) | bin;
            sel[t * 2 + 1] = r - cb;
        }
    }
    if (LEVEL == 2 && lane == 0) {
        float vA = __uint_as_float(sel[4]);
        float vB = __uint_as_float(sel[5]);
        float med = 0.5f * (vA + vB);
        float bw = (med + 1e-6f) * 0.25f;
        #pragma unroll
        for (int k = 0; k < KN; ++k) params[k] = 1.0f / (bw * (float)(1 << k));
    }
}

// ---------------------------------------------------------------- k_wsum_tri (XCD-matched + exp power-chain)
__global__ __launch_bounds__(256) void k_wsum_tri(const float* __restrict__ D,
                                                  const float* __restrict__ params,
                                                  const float* __restrict__ beta,
                                                  double* __restrict__ partials)
{
    if (blockIdx.x == 0) { if (threadIdx.x == 0) partials[NTILES] = 0.0; return; }
    float i4 = params[4];      // 1/(bw*16): widest kernel, smallest exponent
    float b0 = beta[0], b1 = beta[1], b2 = beta[2], b3 = beta[3], b4 = beta[4];
    const double wDiag = 1.0 / ((double)NS * (NS - 1));
    const double wOff = -1.0 / ((double)NS * NS);
    int bx, by;
    tri_map(xcd_tile(blockIdx.x - 1), bx, by);
    int m0 = by * 128, n0 = bx * 128;
    double wt = (bx != by) ? 2.0 : 1.0;
    double acc = 0.0;
    for (int v = threadIdx.x; v < 4096; v += 256) {
        int r = m0 + (v >> 5);
        int c0 = n0 + (v & 31) * 4;
        float4 dv = *(const float4*)&D[(size_t)r * NT + c0];
        const float* dd = (const float*)&dv;
        #pragma unroll
        for (int j = 0; j < 4; ++j) {
            int c = c0 + j;
            if (r == c) continue;
            float sq = dd[j];
            // y = exp(-sq/(bw*16)); exp(-sq/(bw*2^k)) = y^(2^(4-k))
            float y1 = __expf(-sq * i4);
            float y2 = y1 * y1;
            float y4 = y2 * y2;
            float y8 = y4 * y4;
            float y16 = y8 * y8;
            float val = b4 * y1 + b3 * y2 + b2 * y4 + b1 * y8 + b0 * y16;
            bool same = (r < NS) == (c < NS);
            acc += (same ? wDiag : wOff) * (double)val;
        }
    }
    acc *= wt;
    __shared__ double red[256];
    red[threadIdx.x] = acc;
    __syncthreads();
    for (int off = 128; off > 0; off >>= 1) {
        if (threadIdx.x < off) red[threadIdx.x] += red[threadIdx.x + off];
        __syncthreads();
    }
    if (threadIdx.x == 0) partials[blockIdx.x - 1] = red[0];
}

// ---------------------------------------------------------------- k_final
__global__ __launch_bounds__(256) void k_final(const double* __restrict__ partials,
                                               float* __restrict__ out, int count)
{
    double acc = 0;
    for (int i = threadIdx.x; i < count; i += 256) acc += partials[i];
    __shared__ double red[256];
    red[threadIdx.x] = acc;
    __syncthreads();
    for (int off = 128; off > 0; off >>= 1) {
        if (threadIdx.x < off) red[threadIdx.x] += red[threadIdx.x + off];
        __syncthreads();
    }
    if (threadIdx.x == 0) out[0] = (float)fmax(red[0], 0.0);
}

// ---------------------------------------------------------------- launch
extern "C" void kernel_launch(void* const* d_in, const int* in_sizes, int n_in,
                              void* d_out, int out_size, void* d_ws, size_t ws_size,
                              hipStream_t stream)
{
    const float* S = (const float*)d_in[0];
    const float* T = (const float*)d_in[1];
    const float* beta = (const float*)d_in[2];
    float* out = (float*)d_out;

    float* D = (float*)d_ws;                              // 4096*4096 f
    unsigned short* Hi = (unsigned short*)(D + (size_t)NT * NT);
    unsigned short* Lo = Hi + (size_t)NT * DDIM;
    float* norms = (float*)(Lo + (size_t)NT * DDIM);      // 4096 f
    float* g = norms + NT;                                // 5120 f
    float* beta2 = g + 1024 * KN;                         // 8 f
    float* params = beta2 + 8;                            // 8 f
    unsigned* sel = (unsigned*)(params + 8);              // 16 u
    unsigned* hists = sel + 16;                           // 11264 u
    unsigned* hL0 = hists;
    unsigned* hL1A = hists + 1024;
    unsigned* hL1B = hists + 2048;
    unsigned* hL2A = hists + 3072;
    unsigned* hL2B = hists + 7168;
    double* partials = (double*)(hists + 11264);          // 529 d

    k_prep2<<<dim3(256), dim3(256), 0, stream>>>(S, T, Hi, Lo, norms, g, hists, sel);
    k_dist_mfma<<<dim3(NTILES + 1), dim3(256), 0, stream>>>(Hi, Lo, norms, D, g, beta, beta2);
    k_hist0_tri<<<dim3(NTILES + 1), dim3(256), 0, stream>>>(D, hL0);
    k_scan0<<<dim3(1), dim3(64), 0, stream>>>(hL0, sel);
    k_hist_tri<1><<<dim3(NTILES + 1), dim3(256), 0, stream>>>(D, sel, hL1A, hL1B);
    k_scan<1><<<dim3(1), dim3(64), 0, stream>>>(hL1A, hL1B, sel, params);
    k_hist_tri<2><<<dim3(NTILES + 1), dim3(256), 0, stream>>>(D, sel, hL2A, hL2B);
    k_scan<2><<<dim3(1), dim3(64), 0, stream>>>(hL2A, hL2B, sel, params);
    k_wsum_tri<<<dim3(NTILES + 1), dim3(256), 0, stream>>>(D, params, beta2, partials);
    k_final<<<dim3(1), dim3(256), 0, stream>>>(partials, out, NTILES);
}